// Round 4
// baseline (774.217 us; speedup 1.0000x reference)
//
#include <hip/hip_runtime.h>
#include <hip/hip_bf16.h>

#define G1 __attribute__((address_space(1)))
#define L3 __attribute__((address_space(3)))

typedef __bf16 bf16x8 __attribute__((ext_vector_type(8)));
typedef _Float16 half4 __attribute__((ext_vector_type(4)));
typedef float f32x4 __attribute__((ext_vector_type(4)));

__device__ __forceinline__ ushort f2bf(float f) {
  union { float f; uint u; } v; v.f = f;
  uint u = v.u;
  u += 0x7fffu + ((u >> 16) & 1u);   // RNE
  return (ushort)(u >> 16);
}
__device__ __forceinline__ ushort f2h(float f) {
  _Float16 h = (_Float16)f;
  union { _Float16 h; ushort u; } v; v.h = h;
  return v.u;
}

// ---------------- cast fp32 -> bf16 ----------------
__global__ void cast_bf16_kernel(const float* __restrict__ in, ushort* __restrict__ out, int n4) {
  int i = blockIdx.x * 256 + threadIdx.x;
  if (i >= n4) return;
  float4 v = ((const float4*)in)[i];
  ushort4 o;
  o.x = f2bf(v.x); o.y = f2bf(v.y); o.z = f2bf(v.z); o.w = f2bf(v.w);
  ((ushort4*)out)[i] = o;
}

// ---------------- bt-GEMM: out[m][n] = sum_k A[m][k]*B[n][k] + bias[n] ----------------
// MODE 2: out fp32 row-major [m][n]
// MODE 3: fused QKV: n<2048 -> Q bf16 (bh,t,d); n<4096 -> K bf16 (bh,t,d); else V fp16 (bh,d,t)
template <int MODE>
__global__ __launch_bounds__(256, 2)
void gemm_bt(const ushort* __restrict__ A, const ushort* __restrict__ Bm,
             const float* __restrict__ bias, void* __restrict__ outp,
             void* __restrict__ out2, void* __restrict__ out3,
             int M, int N, int K) {
  __shared__ ushort As[128 * 32];
  __shared__ ushort Bs[128 * 32];
  const int tid  = threadIdx.x;
  const int wave = tid >> 6, lane = tid & 63;
  const int l15  = lane & 15, quad = lane >> 4;
  const int m0 = blockIdx.x * 128, n0 = blockIdx.y * 128;
  const int wm = (wave & 1) * 64, wn = (wave >> 1) * 64;

  f32x4 acc[4][4] = {};
  for (int k0 = 0; k0 < K; k0 += 32) {
    __syncthreads();
#pragma unroll
    for (int i = 0; i < 2; ++i) {
      int c = (wave * 2 + i) * 64 + lane;     // 16B chunk id, 0..511
      int row = c >> 2, cib = c & 3;
      const ushort* ga = A  + (size_t)(m0 + row) * K + k0 + cib * 8;
      const ushort* gb = Bm + (size_t)(n0 + row) * K + k0 + cib * 8;
      __builtin_amdgcn_global_load_lds((G1 uint*)ga, (L3 uint*)&As[c * 8], 16, 0, 0);
      __builtin_amdgcn_global_load_lds((G1 uint*)gb, (L3 uint*)&Bs[c * 8], 16, 0, 0);
    }
    __syncthreads();
    bf16x8 af[4], bfr[4];
#pragma unroll
    for (int mi = 0; mi < 4; ++mi)
      af[mi]  = *(const bf16x8*)&As[(wm + mi * 16 + l15) * 32 + quad * 8];
#pragma unroll
    for (int ni = 0; ni < 4; ++ni)
      bfr[ni] = *(const bf16x8*)&Bs[(wn + ni * 16 + l15) * 32 + quad * 8];
#pragma unroll
    for (int ni = 0; ni < 4; ++ni)
#pragma unroll
      for (int mi = 0; mi < 4; ++mi)
        acc[mi][ni] = __builtin_amdgcn_mfma_f32_16x16x32_bf16(af[mi], bfr[ni], acc[mi][ni], 0, 0, 0);
  }

#pragma unroll
  for (int mi = 0; mi < 4; ++mi)
#pragma unroll
    for (int ni = 0; ni < 4; ++ni) {
      int n = n0 + wn + ni * 16 + l15;
      float bv = bias[n];
#pragma unroll
      for (int r = 0; r < 4; ++r) {
        int m = m0 + wm + mi * 16 + quad * 4 + r;   // C/D: row = quad*4+reg, col = l15 (m89/m91)
        float v = acc[mi][ni][r] + bv;
        if (MODE == 2) {
          ((float*)outp)[(size_t)m * N + n] = v;
        } else {
          int sel = n >> 11;                // wave-uniform per ni (16-col group)
          int nh = n & 2047, h = nh >> 7, dd = nh & 127;
          int b = m >> 11, t = m & 2047;
          if (sel == 0)
            ((ushort*)outp)[(((size_t)(b * 16 + h) * 2048 + t) << 7) + dd] = f2bf(v);
          else if (sel == 1)
            ((ushort*)out2)[(((size_t)(b * 16 + h) * 2048 + t) << 7) + dd] = f2bf(v);
          else
            ((ushort*)out3)[(((size_t)(b * 16 + h) * 128 + dd) << 11) + t] = f2h(v);
        }
      }
    }
}

// ---------------- flash attention (S^T form, paired q-tiles) ----------------
// Q,K: (bh,t,d) bf16.  Vt: (bh,d,t) fp16.  Y: (b,t,C) bf16.
// block = (bh, y): processes q-tiles {15-y, y} sequentially -> uniform 36 tile-iters/block.
__global__ __launch_bounds__(256, 3)
void attn_kernel(const ushort* __restrict__ Q, const ushort* __restrict__ Kh,
                 const ushort* __restrict__ Vt, const float* __restrict__ mask,
                 ushort* __restrict__ Y) {
  __shared__ ushort Ks[64 * 128];   // XOR-swizzled 16B chunks: (t, ck) at t*16 + (ck^(t&15))
  __shared__ ushort Vs[128 * 64];   // XOR-swizzled: (d, ck) at d*8 + (ck^(d&7))
  const int tid  = threadIdx.x;
  const int wave = tid >> 6, lane = tid & 63;
  const int l15  = lane & 15, quad = lane >> 4;
  const int bh = blockIdx.x;
  const int b  = bh >> 4, h = bh & 15;
  const ushort* Qb = Q  + (size_t)bh * 2048 * 128;
  const ushort* Kb = Kh + (size_t)bh * 2048 * 128;
  const ushort* Vb = Vt + (size_t)bh * 128 * 2048;
  const float*  mrow = mask + b * 2048;
  const float scale = 0.08838834764831845f;  // 1/sqrt(128)

  for (int phase = 0; phase < 2; ++phase) {
    const int qt  = phase ? (int)blockIdx.y : 15 - (int)blockIdx.y;
    const int qw0 = qt * 128 + wave * 32;

    // Q B-frags (persistent per phase): lane l15 = qr, k=d = dk*32+quad*8..+7
    bf16x8 aq[2][4];
#pragma unroll
    for (int q2 = 0; q2 < 2; ++q2)
#pragma unroll
      for (int dk = 0; dk < 4; ++dk)
        aq[q2][dk] = *(const bf16x8*)(Qb + (size_t)(qw0 + q2 * 16 + l15) * 128 + dk * 32 + quad * 8);

    float mi_[2], li[2];
    f32x4 OT[8][2] = {};   // OT[ddt][q2]: rows dd=ddt*16+quad*4+r, cols qr=q2*16+l15
    mi_[0] = mi_[1] = -3.0e38f;
    li[0] = li[1] = 0.f;

    const int nkt = 2 * qt + 2;
    for (int it = 0; it < nkt; ++it) {
      const int k0 = it * 64;
      __syncthreads();
      // stage K tile (64 t x 128 d, 16KB) swizzled
#pragma unroll
      for (int i = 0; i < 4; ++i) {
        int c = i * 256 + tid;                      // LDS 16B-chunk 0..1023
        int t = c >> 4, ckG = (c & 15) ^ (t & 15);
        __builtin_amdgcn_global_load_lds((G1 uint*)(Kb + (size_t)(k0 + t) * 128 + ckG * 8),
                                         (L3 uint*)&Ks[c * 8], 16, 0, 0);
      }
      // stage V tile (128 d x 64 t, 16KB) swizzled
#pragma unroll
      for (int i = 0; i < 4; ++i) {
        int c = i * 256 + tid;
        int d = c >> 3, ckG = (c & 7) ^ (d & 7);
        __builtin_amdgcn_global_load_lds((G1 uint*)(Vb + (size_t)d * 2048 + k0 + ckG * 8),
                                         (L3 uint*)&Vs[c * 8], 16, 0, 0);
      }
      __syncthreads();

      if (k0 <= qw0 + 31) {    // tile intersects this wave's causal range
        float4 mk[4];
#pragma unroll
        for (int ns = 0; ns < 4; ++ns)
          mk[ns] = *(const float4*)&mrow[k0 + ns * 16 + quad * 4];

        // S^T = K.Q^T ; dk OUTER so same-acc MFMA dep distance = 8
        f32x4 s[2][4] = {};
#pragma unroll
        for (int dk = 0; dk < 4; ++dk) {
          bf16x8 kb[4];
#pragma unroll
          for (int ns = 0; ns < 4; ++ns) {
            int ck = ((dk * 4 + quad) ^ l15);
            kb[ns] = *(const bf16x8*)&Ks[(ns * 16 + l15) * 128 + ck * 8];
          }
#pragma unroll
          for (int ns = 0; ns < 4; ++ns)
#pragma unroll
            for (int q2 = 0; q2 < 2; ++q2)
              s[q2][ns] = __builtin_amdgcn_mfma_f32_16x16x32_bf16(kb[ns], aq[q2][dk], s[q2][ns], 0, 0, 0);
        }

        // scale + mask + causal; element: kc = k0+16ns+quad*4+r, qr = qw0+q2*16+l15
        half4 pf[2][4];
#pragma unroll
        for (int q2 = 0; q2 < 2; ++q2) {
          const int qr = qw0 + q2 * 16 + l15;
#pragma unroll
          for (int ns = 0; ns < 4; ++ns)
#pragma unroll
            for (int r = 0; r < 4; ++r) {
              int kc = k0 + ns * 16 + quad * 4 + r;
              float v = s[q2][ns][r] * scale + mk[ns][r];
              s[q2][ns][r] = (kc > qr) ? -3.0e38f : v;
            }
          float rm = -3.0e38f;
#pragma unroll
          for (int ns = 0; ns < 4; ++ns)
            rm = fmaxf(rm, fmaxf(fmaxf(s[q2][ns][0], s[q2][ns][1]), fmaxf(s[q2][ns][2], s[q2][ns][3])));
          rm = fmaxf(rm, __shfl_xor(rm, 16));
          rm = fmaxf(rm, __shfl_xor(rm, 32));
          float mnew = fmaxf(mi_[q2], rm);
          float al = __expf(mi_[q2] - mnew);
          float rs = 0.f;
#pragma unroll
          for (int ns = 0; ns < 4; ++ns) {
#pragma unroll
            for (int r = 0; r < 4; ++r) {
              float p = __expf(s[q2][ns][r] - mnew);
              s[q2][ns][r] = p;
              rs += p;
            }
            pf[q2][ns] = half4{(_Float16)s[q2][ns][0], (_Float16)s[q2][ns][1],
                               (_Float16)s[q2][ns][2], (_Float16)s[q2][ns][3]};
          }
          rs += __shfl_xor(rs, 16);
          rs += __shfl_xor(rs, 32);
          li[q2] = li[q2] * al + rs;
          mi_[q2] = mnew;
#pragma unroll
          for (int ddt = 0; ddt < 8; ++ddt) OT[ddt][q2] *= al;
        }

        // PV: OT[ddt][q2] += mfma_16x16x16_f16(A=V^T frag, B=P frag); acc reuse distance 16
#pragma unroll
        for (int ns = 0; ns < 4; ++ns)
#pragma unroll
          for (int ddt = 0; ddt < 8; ++ddt) {
            int row = ddt * 16 + l15;
            int ck = (2 * ns + (quad >> 1)) ^ (l15 & 7);
            half4 vf = *(const half4*)&Vs[row * 64 + ck * 8 + (quad & 1) * 4];
#pragma unroll
            for (int q2 = 0; q2 < 2; ++q2)
              OT[ddt][q2] = __builtin_amdgcn_mfma_f32_16x16x16f16(vf, pf[q2][ns], OT[ddt][q2], 0, 0, 0);
          }
      }
    }

    // epilogue for this phase
#pragma unroll
    for (int q2 = 0; q2 < 2; ++q2) {
      float inv = 1.0f / li[q2];
      int t = qw0 + q2 * 16 + l15;
#pragma unroll
      for (int ddt = 0; ddt < 8; ++ddt) {
        ushort4 o;
        o.x = f2bf(OT[ddt][q2][0] * inv);
        o.y = f2bf(OT[ddt][q2][1] * inv);
        o.z = f2bf(OT[ddt][q2][2] * inv);
        o.w = f2bf(OT[ddt][q2][3] * inv);
        *(ushort4*)&Y[((size_t)(b * 2048 + t)) * 2048 + h * 128 + ddt * 16 + quad * 4] = o;
      }
    }
  }
}

extern "C" void kernel_launch(void* const* d_in, const int* in_sizes, int n_in,
                              void* d_out, int out_size, void* d_ws, size_t ws_size,
                              hipStream_t stream) {
  const float* x     = (const float*)d_in[0];
  const float* amask = (const float*)d_in[1];
  const float* Wq = (const float*)d_in[2];
  const float* bq = (const float*)d_in[3];
  const float* Wk = (const float*)d_in[4];
  const float* bk = (const float*)d_in[5];
  const float* Wv = (const float*)d_in[6];
  const float* bv = (const float*)d_in[7];
  const float* Wp = (const float*)d_in[8];
  const float* bp = (const float*)d_in[9];

  char* ws = (char*)d_ws;
  ushort* xb    = (ushort*)(ws);                   // [0,32MB)   x bf16 (8192x2048)
  ushort* Yb    = (ushort*)(ws);                   // aliases xb (x dead after QKV GEMM)
  ushort* Wqkvb = (ushort*)(ws + 33554432);        // [32,56MB)  stacked Wq|Wk|Wv bf16 (6144x2048)
  ushort* Wpb   = (ushort*)(ws + 58720256);        // [56,64MB)
  float*  bqkv  = (float*)(ws + 67108864);         // [64MB, +24KB) concat bq|bk|bv
  ushort* Qb    = (ushort*)(ws + 100663296);       // [96,128MB)  (bh,t,d) bf16
  ushort* Kb    = (ushort*)(ws + 134217728);       // [128,160MB) (bh,t,d) bf16
  ushort* Vtb   = (ushort*)(ws + 167772160);       // [160,192MB) (bh,d,t) fp16

  hipMemcpyAsync(bqkv,        bq, 2048 * 4, hipMemcpyDeviceToDevice, stream);
  hipMemcpyAsync(bqkv + 2048, bk, 2048 * 4, hipMemcpyDeviceToDevice, stream);
  hipMemcpyAsync(bqkv + 4096, bv, 2048 * 4, hipMemcpyDeviceToDevice, stream);

  cast_bf16_kernel<<<16384, 256, 0, stream>>>(x,  xb,  4194304);
  cast_bf16_kernel<<<4096,  256, 0, stream>>>(Wq, Wqkvb,           1048576);
  cast_bf16_kernel<<<4096,  256, 0, stream>>>(Wk, Wqkvb + 4194304, 1048576);
  cast_bf16_kernel<<<4096,  256, 0, stream>>>(Wv, Wqkvb + 8388608, 1048576);
  cast_bf16_kernel<<<4096,  256, 0, stream>>>(Wp, Wpb,             1048576);

  // fused QKV: M=8192, N=6144, K=2048
  gemm_bt<3><<<dim3(64, 48), 256, 0, stream>>>(xb, Wqkvb, bqkv, Qb, Kb, Vtb, 8192, 6144, 2048);

  attn_kernel<<<dim3(64, 8), 256, 0, stream>>>(Qb, Kb, Vtb, amask, Yb);

  gemm_bt<2><<<dim3(64, 16), 256, 0, stream>>>(Yb, Wpb, bp, d_out, nullptr, nullptr, 8192, 2048, 2048);
}